// Round 3
// baseline (3354.910 us; speedup 1.0000x reference)
//
#include <hip/hip_runtime.h>

// InternLM2VE decoder layer, MI355X gfx950.
// R3: inputs/outputs are FLOAT32 (per reference setup_inputs). Internal
// compute uses bf16 MFMA (harness threshold has a bf16-ULP floor).
// H=2048, NH=16, NKV=8, HD=128, S=2048, FF=8192, B=1.
// d_out (f32) = [ out (2048x2048) | residual (2048x2048) ].

typedef __bf16 bf16_t;
typedef __bf16 bf16x8 __attribute__((ext_vector_type(8)));
typedef float f32x4 __attribute__((ext_vector_type(4)));

// ---------------------------------------------------------------------------
// Tiled transpose + cast f32->bf16: Wt[row_off+n][k] = W[k][n].
// ---------------------------------------------------------------------------
__global__ __launch_bounds__(256) void transpose_k(const float* __restrict__ W,
                                                   bf16_t* __restrict__ Wt,
                                                   int K, int N, int row_off) {
  __shared__ bf16_t tile[32][34];  // stride 68B: no pow-2 bank aliasing
  const int tx = threadIdx.x & 31, ty = threadIdx.x >> 5;
  const int n0 = blockIdx.x * 32, k0 = blockIdx.y * 32;
#pragma unroll
  for (int i = 0; i < 4; i++)
    tile[ty + 8 * i][tx] = (bf16_t)W[(size_t)(k0 + ty + 8 * i) * N + n0 + tx];
  __syncthreads();
#pragma unroll
  for (int i = 0; i < 4; i++)
    Wt[(size_t)(row_off + n0 + ty + 8 * i) * K + k0 + tx] = tile[tx][ty + 8 * i];
}

// ---------------------------------------------------------------------------
// RMSNorm row: y = bf16( x * rsqrt(mean(x^2)+eps) * w )   (f32 in, bf16 out)
// ---------------------------------------------------------------------------
__global__ __launch_bounds__(256) void rmsnorm_k(const float* __restrict__ x,
                                                 const float* __restrict__ w,
                                                 bf16_t* __restrict__ y) {
  const int row = blockIdx.x, t = threadIdx.x;
  __shared__ float red[256];
  float vals[8];
  float ss = 0.f;
  const float* xr = x + (size_t)row * 2048;
#pragma unroll
  for (int i = 0; i < 8; i++) {
    float v = xr[t + 256 * i];
    vals[i] = v;
    ss += v * v;
  }
  red[t] = ss;
  __syncthreads();
  for (int s = 128; s > 0; s >>= 1) {
    if (t < s) red[t] += red[t + s];
    __syncthreads();
  }
  const float scale = rsqrtf(red[0] * (1.f / 2048.f) + 1e-6f);
  bf16_t* yr = y + (size_t)row * 2048;
#pragma unroll
  for (int i = 0; i < 8; i++)
    yr[t + 256 * i] = (bf16_t)(vals[i] * scale * w[t + 256 * i]);
}

// ---------------------------------------------------------------------------
// RoPE on bf16 qkv buffer (row = 4096: q[16*128] | k[8*128] | v[8*128]).
// cos/sin are f32 (S x 128).  grid (S, 32): 0..15 q in-place, 16..23 k->kb,
// 24..31 v->vb.
// ---------------------------------------------------------------------------
__global__ __launch_bounds__(128) void rope_k(bf16_t* __restrict__ qkv,
                                              const float* __restrict__ cosb,
                                              const float* __restrict__ sinb,
                                              bf16_t* __restrict__ kb,
                                              bf16_t* __restrict__ vb) {
  const int s = blockIdx.x, head = blockIdx.y, d = threadIdx.x;
  if (head < 16) {
    bf16_t* qp = qkv + (size_t)s * 4096 + head * 128;
    const float x = (float)qp[d];
    const float partner = (float)qp[d ^ 64];
    const float rot = (d < 64) ? -partner : partner;
    const float c = cosb[s * 128 + d], sn = sinb[s * 128 + d];
    __syncthreads();  // head is block-uniform; reads before in-place writes
    qp[d] = (bf16_t)(x * c + rot * sn);
  } else if (head < 24) {
    const int kvh = head - 16;
    const bf16_t* kp = qkv + (size_t)s * 4096 + 2048 + kvh * 128;
    const float x = (float)kp[d];
    const float partner = (float)kp[d ^ 64];
    const float rot = (d < 64) ? -partner : partner;
    const float c = cosb[s * 128 + d], sn = sinb[s * 128 + d];
    kb[(size_t)s * 1024 + kvh * 128 + d] = (bf16_t)(x * c + rot * sn);
  } else {
    const int kvh = head - 24;
    vb[(size_t)s * 1024 + kvh * 128 + d] = qkv[(size_t)s * 4096 + 3072 + kvh * 128 + d];
  }
}

// ---------------------------------------------------------------------------
// Causal GQA attention, correctness-first: one block per (query, head).
// ---------------------------------------------------------------------------
__global__ __launch_bounds__(128) void attn_k(const bf16_t* __restrict__ qb,
                                              const bf16_t* __restrict__ kb,
                                              const bf16_t* __restrict__ vb,
                                              bf16_t* __restrict__ ob) {
  const int qpos = blockIdx.x, h = blockIdx.y, kvh = h >> 1;
  const int t = threadIdx.x;
  __shared__ float qs[128];
  __shared__ float sc[2048];
  __shared__ float red[128];
  qs[t] = (float)qb[(size_t)qpos * 4096 + h * 128 + t] * 0.08838834764831845f;
  __syncthreads();
  const int nk = qpos + 1;
  float lmax = -1e30f;
  for (int j = t; j < nk; j += 128) {
    const bf16_t* kr = kb + (size_t)j * 1024 + kvh * 128;
    float dot = 0.f;
#pragma unroll
    for (int c = 0; c < 16; c++) {
      bf16x8 kv8 = *(const bf16x8*)(kr + c * 8);
#pragma unroll
      for (int e = 0; e < 8; e++) dot += qs[c * 8 + e] * (float)kv8[e];
    }
    sc[j] = dot;
    lmax = fmaxf(lmax, dot);
  }
  red[t] = lmax;
  __syncthreads();
  for (int s = 64; s > 0; s >>= 1) {
    if (t < s) red[t] = fmaxf(red[t], red[t + s]);
    __syncthreads();
  }
  const float m = red[0];
  __syncthreads();
  float lsum = 0.f;
  for (int j = t; j < nk; j += 128) {
    const float p = __expf(sc[j] - m);
    sc[j] = p;
    lsum += p;
  }
  red[t] = lsum;
  __syncthreads();
  for (int s = 64; s > 0; s >>= 1) {
    if (t < s) red[t] += red[t + s];
    __syncthreads();
  }
  const float inv = 1.f / red[0];
  const bf16_t* vcol = vb + kvh * 128 + t;  // lane t consecutive: coalesced
  float o0 = 0.f, o1 = 0.f, o2 = 0.f, o3 = 0.f;
  int j = 0;
  for (; j + 4 <= nk; j += 4) {
    o0 += sc[j] * (float)vcol[(size_t)j * 1024];
    o1 += sc[j + 1] * (float)vcol[(size_t)(j + 1) * 1024];
    o2 += sc[j + 2] * (float)vcol[(size_t)(j + 2) * 1024];
    o3 += sc[j + 3] * (float)vcol[(size_t)(j + 3) * 1024];
  }
  for (; j < nk; j++) o0 += sc[j] * (float)vcol[(size_t)j * 1024];
  ob[(size_t)qpos * 2048 + h * 128 + t] = (bf16_t)(((o0 + o1) + (o2 + o3)) * inv);
}

// ---------------------------------------------------------------------------
// bf16 MFMA GEMM: C[M,N] = A[M,K] @ Bt[N,K]^T, 128x128 tile, BK=32, 4 waves.
// Explicit bf16x8 load -> ds_write staging; 16B-chunk XOR bank swizzle.
// A rows gathered via a_idx; C rows scattered via c_idx (both optional).
// mode 0: Cf = acc                        [down proj -> f32 out]
// mode 1: Cf = acc + Rf                   [o-proj + residual, f32]
// mode 2: Cb = bf16(silu(Gb) * acc)       [SwiGLU up fuse]
// mode 3: Cb = bf16(acc)                  [QKV, gate]
// ---------------------------------------------------------------------------
__global__ __launch_bounds__(256) void gemm_bt(
    const bf16_t* __restrict__ A, int lda, const int* __restrict__ a_idx,
    const bf16_t* __restrict__ Bt, int K,
    float* __restrict__ Cf, bf16_t* __restrict__ Cb,
    const int* __restrict__ c_idx, int ldc, int mode,
    const bf16_t* __restrict__ Gb, const float* __restrict__ Rf) {
  __shared__ __align__(16) bf16_t As[128 * 32];
  __shared__ __align__(16) bf16_t Bs[128 * 32];
  __shared__ int arows[128];

  const int t = threadIdx.x;
  const int row0 = blockIdx.y * 128, col0 = blockIdx.x * 128;

  if (t < 128) arows[t] = a_idx ? a_idx[row0 + t] : (row0 + t);
  __syncthreads();

  // 512 16B segments per 128x32 tile; seg = p*256+t; m=seg>>2; LDS slot
  // c=seg&3 holds global k-chunk q = c ^ ((m>>1)&3)   (bank swizzle)
  const int sm0 = t >> 2;
  const int sq0 = (((t & 3) ^ ((sm0 >> 1) & 3)) << 3);
  const int sm1 = (t + 256) >> 2;
  const int sq1 = ((((t + 256) & 3) ^ ((sm1 >> 1) & 3)) << 3);

  const bf16_t* gA0 = A + (size_t)arows[sm0] * lda + sq0;
  const bf16_t* gA1 = A + (size_t)arows[sm1] * lda + sq1;
  const bf16_t* gB0 = Bt + (size_t)(col0 + sm0) * K + sq0;
  const bf16_t* gB1 = Bt + (size_t)(col0 + sm1) * K + sq1;
  bf16x8* lA0 = (bf16x8*)(As + t * 8);
  bf16x8* lA1 = (bf16x8*)(As + (t + 256) * 8);
  bf16x8* lB0 = (bf16x8*)(Bs + t * 8);
  bf16x8* lB1 = (bf16x8*)(Bs + (t + 256) * 8);

  const int wid = t >> 6, lane = t & 63;
  const int wm = (wid & 1) << 6, wn = (wid >> 1) << 6;
  const int lrow = lane & 15, lq = lane >> 4;

  int a_off[4], b_off[4];
#pragma unroll
  for (int i = 0; i < 4; i++) {
    const int m = wm + i * 16 + lrow;
    a_off[i] = m * 64 + ((lq ^ ((m >> 1) & 3)) << 4);  // bytes
    const int n = wn + i * 16 + lrow;
    b_off[i] = n * 64 + ((lq ^ ((n >> 1) & 3)) << 4);
  }

  f32x4 acc[4][4];
#pragma unroll
  for (int i = 0; i < 4; i++)
#pragma unroll
    for (int j = 0; j < 4; j++) acc[i][j] = f32x4{0.f, 0.f, 0.f, 0.f};

  for (int k0 = 0; k0 < K; k0 += 32) {
    const bf16x8 ra0 = *(const bf16x8*)(gA0 + k0);
    const bf16x8 ra1 = *(const bf16x8*)(gA1 + k0);
    const bf16x8 rb0 = *(const bf16x8*)(gB0 + k0);
    const bf16x8 rb1 = *(const bf16x8*)(gB1 + k0);
    __syncthreads();  // prior iteration's fragment reads complete
    *lA0 = ra0;
    *lA1 = ra1;
    *lB0 = rb0;
    *lB1 = rb1;
    __syncthreads();  // staging visible
    bf16x8 af[4], bfr[4];
#pragma unroll
    for (int i = 0; i < 4; i++)
      af[i] = *(const bf16x8*)((const char*)As + a_off[i]);
#pragma unroll
    for (int i = 0; i < 4; i++)
      bfr[i] = *(const bf16x8*)((const char*)Bs + b_off[i]);
#pragma unroll
    for (int i = 0; i < 4; i++)
#pragma unroll
      for (int j = 0; j < 4; j++)
        acc[i][j] =
            __builtin_amdgcn_mfma_f32_16x16x32_bf16(af[i], bfr[j], acc[i][j], 0, 0, 0);
  }

#pragma unroll
  for (int i = 0; i < 4; i++) {
#pragma unroll
    for (int r = 0; r < 4; r++) {
      const int gm = row0 + wm + i * 16 + lq * 4 + r;  // C/D: row=(lane>>4)*4+r
      const int crow = c_idx ? c_idx[gm] : gm;
      const size_t base = (size_t)crow * ldc;
#pragma unroll
      for (int j = 0; j < 4; j++) {
        const int col = col0 + wn + j * 16 + lrow;  // C/D: col=lane&15
        float v = acc[i][j][r];
        if (mode == 0) {
          Cf[base + col] = v;
        } else if (mode == 1) {
          Cf[base + col] = v + Rf[base + col];
        } else if (mode == 2) {
          const float g = (float)Gb[base + col];
          Cb[base + col] = (bf16_t)(v * g / (1.f + __expf(-g)));
        } else {
          Cb[base + col] = (bf16_t)v;
        }
      }
    }
  }
}

// ---------------------------------------------------------------------------
extern "C" void kernel_launch(void* const* d_in, const int* in_sizes, int n_in,
                              void* d_out, int out_size, void* d_ws, size_t ws_size,
                              hipStream_t stream) {
  const float* hidden = (const float*)d_in[0];
  const float* cosb = (const float*)d_in[1];
  const float* sinb = (const float*)d_in[2];
  const float* wq = (const float*)d_in[3];
  const float* wk = (const float*)d_in[4];
  const float* wv = (const float*)d_in[5];
  const float* wo = (const float*)d_in[6];
  const float* w1 = (const float*)d_in[7];
  const float* w3 = (const float*)d_in[8];
  const float* w2 = (const float*)d_in[9];
  const float* v1 = (const float*)d_in[10];
  const float* v3 = (const float*)d_in[11];
  const float* v2 = (const float*)d_in[12];
  const float* anw = (const float*)d_in[13];
  const float* fnw = (const float*)d_in[14];
  const int* vidx = (const int*)d_in[15];
  const int* tidx = (const int*)d_in[16];

  float* out0 = (float*)d_out;                // MLP output [2048][2048] f32
  float* outr = out0 + (size_t)2048 * 2048;   // residual   [2048][2048] f32

  // ws layout (72 MB), all bf16 intermediates; offsets in MB
  char* wsb = (char*)d_ws;
  const size_t MB = 1024 * 1024;
  bf16_t* qkvb = (bf16_t*)(wsb + 0 * MB);    // [0,16): QKV out, q roped in place
  bf16_t* kb = (bf16_t*)(wsb + 16 * MB);     // [16,20)
  bf16_t* vb = (bf16_t*)(wsb + 20 * MB);     // [20,24)
  bf16_t* attnb = (bf16_t*)(wsb + 24 * MB);  // [24,32)
  bf16_t* hn = (bf16_t*)(wsb + 32 * MB);     // [32,40): norm out (attn, then ffn)
  bf16_t* g = (bf16_t*)(wsb + 0 * MB);       // [0,16): gate (qkvb dead)
  bf16_t* act = (bf16_t*)(wsb + 16 * MB);    // [16,32): silu*up (kb/vb/attnb dead)
  bf16_t* bufT = (bf16_t*)(wsb + 40 * MB);   // [40,72): transposed bf16 weights

  // --- attention block ---
  transpose_k<<<dim3(64, 64), 256, 0, stream>>>(wq, bufT, 2048, 2048, 0);
  transpose_k<<<dim3(32, 64), 256, 0, stream>>>(wk, bufT, 2048, 1024, 2048);
  transpose_k<<<dim3(32, 64), 256, 0, stream>>>(wv, bufT, 2048, 1024, 3072);
  rmsnorm_k<<<2048, 256, 0, stream>>>(hidden, anw, hn);
  gemm_bt<<<dim3(32, 16), 256, 0, stream>>>(hn, 2048, nullptr, bufT, 2048, nullptr,
                                            qkvb, nullptr, 4096, 3, nullptr, nullptr);
  rope_k<<<dim3(2048, 32), 128, 0, stream>>>(qkvb, cosb, sinb, kb, vb);
  attn_k<<<dim3(2048, 16), 128, 0, stream>>>(qkvb, kb, vb, attnb);
  transpose_k<<<dim3(64, 64), 256, 0, stream>>>(wo, bufT, 2048, 2048, 0);
  gemm_bt<<<dim3(16, 16), 256, 0, stream>>>(attnb, 2048, nullptr, bufT, 2048, outr,
                                            nullptr, nullptr, 2048, 1, nullptr, hidden);
  // --- FFN block (residual re-read f32 from d_out; vision rows, then text) ---
  rmsnorm_k<<<2048, 256, 0, stream>>>(outr, fnw, hn);
  const float* Wg[2] = {v1, w1};
  const float* Wu[2] = {v3, w3};
  const float* Wd[2] = {v2, w2};
  const int* idx[2] = {vidx, tidx};
  for (int hh = 0; hh < 2; hh++) {
    transpose_k<<<dim3(256, 64), 256, 0, stream>>>(Wg[hh], bufT, 2048, 8192, 0);
    gemm_bt<<<dim3(64, 8), 256, 0, stream>>>(hn, 2048, idx[hh], bufT, 2048, nullptr,
                                             g, nullptr, 8192, 3, nullptr, nullptr);
    transpose_k<<<dim3(256, 64), 256, 0, stream>>>(Wu[hh], bufT, 2048, 8192, 0);
    gemm_bt<<<dim3(64, 8), 256, 0, stream>>>(hn, 2048, idx[hh], bufT, 2048, nullptr,
                                             act, nullptr, 8192, 2, g, nullptr);
    transpose_k<<<dim3(64, 256), 256, 0, stream>>>(Wd[hh], bufT, 8192, 2048, 0);
    gemm_bt<<<dim3(16, 8), 256, 0, stream>>>(act, 8192, nullptr, bufT, 8192, out0,
                                             nullptr, idx[hh], 2048, 0, nullptr,
                                             nullptr);
  }
}